// Round 1
// baseline (1681.749 us; speedup 1.0000x reference)
//
#include <hip/hip_runtime.h>
#include <hip/hip_bf16.h>

#define BB 32
#define NN 512
#define DA 100
#define DIN 64
#define HH 128
#define E1 4
#define DOUT 16
#define NPROP 5
#define NS2V 3

// ---------------- pack A: L[b,m,n,e] != 0 -> bit n of Abits[((b*E1+e)*N+m)*16 + n/32]
__global__ void pack_A_kernel(const float* __restrict__ L, unsigned* __restrict__ Abits) {
    int t = blockIdx.x * blockDim.x + threadIdx.x;   // (b, m, w)
    if (t >= BB * NN * (NN / 32)) return;
    int w = t & 15;
    int m = (t >> 4) & (NN - 1);
    int b = t >> (4 + 9);
    const float* src = L + ((size_t)(b * NN + m) * NN + 32 * w) * E1;
    unsigned bits[E1] = {0u, 0u, 0u, 0u};
    #pragma unroll 8
    for (int j = 0; j < 32; ++j) {
        float4 v = *reinterpret_cast<const float4*>(src + j * 4);
        if (v.x != 0.f) bits[0] |= (1u << j);
        if (v.y != 0.f) bits[1] |= (1u << j);
        if (v.z != 0.f) bits[2] |= (1u << j);
        if (v.w != 0.f) bits[3] |= (1u << j);
    }
    #pragma unroll
    for (int e = 0; e < E1; ++e)
        Abits[((b * E1 + e) * NN + m) * 16 + w] = bits[e];
}

// ---------------- transpose edge_emb into Linear-style Wt[Nc][Kc]: Wmsg[(e*H+k)*H+h] = edge_emb[e, h*H+k]
__global__ void transposeW_kernel(const float* __restrict__ EE, float* __restrict__ Wmsg) {
    int t = blockIdx.x * blockDim.x + threadIdx.x;
    if (t >= E1 * HH * HH) return;
    int h = t & (HH - 1);
    int k = (t >> 7) & (HH - 1);
    int e = t >> 14;
    Wmsg[t] = EE[e * HH * HH + h * HH + k];
}

// ---------------- embed: state[row, h] = node_emb[nf[row]] . W_in[h,:] + b_in[h]
__global__ void embed_kernel(const int* __restrict__ nf, const float* __restrict__ emb,
                             const float* __restrict__ Win, const float* __restrict__ bin,
                             float* __restrict__ state) {
    int row = blockIdx.x;
    int h = threadIdx.x;
    __shared__ float e[DIN];
    int a = nf[row];
    if (h < DIN) e[h] = emb[a * DIN + h];
    __syncthreads();
    float acc = bin[h];
    const float* w = Win + h * DIN;
    #pragma unroll
    for (int d = 0; d < DIN; ++d) acc = fmaf(e[d], w[d], acc);
    state[row * HH + h] = acc;
}

// ---------------- generic fp32 GEMM: C[M x Nc] = X[M x KC] @ Wt[Nc x KC]^T (+bias)
// BM=64 BN=64 BK=32, 256 threads, 4x4 micro-tile
template <int KC>
__global__ __launch_bounds__(256) void gemm_kernel(const float* __restrict__ X,
                                                   const float* __restrict__ Wt,
                                                   const float* __restrict__ bias,
                                                   float* __restrict__ C, int Nc) {
    __shared__ float Xs[32][68];   // [k][m]
    __shared__ float Ws[32][68];   // [k][n]
    int tid = threadIdx.x;
    int tx = tid & 15, ty = tid >> 4;
    int row0 = blockIdx.y * 64, col0 = blockIdx.x * 64;
    float acc[4][4] = {};
    for (int k0 = 0; k0 < KC; k0 += 32) {
        #pragma unroll
        for (int q = 0; q < 2; ++q) {
            int fp = q * 256 + tid;        // float4 index 0..511
            int r = fp >> 3;               // 8 float4 per 32-wide row
            int c = (fp & 7) * 4;
            float4 xv = *reinterpret_cast<const float4*>(X + (size_t)(row0 + r) * KC + k0 + c);
            Xs[c + 0][r] = xv.x; Xs[c + 1][r] = xv.y; Xs[c + 2][r] = xv.z; Xs[c + 3][r] = xv.w;
            float4 wv = *reinterpret_cast<const float4*>(Wt + (size_t)(col0 + r) * KC + k0 + c);
            Ws[c + 0][r] = wv.x; Ws[c + 1][r] = wv.y; Ws[c + 2][r] = wv.z; Ws[c + 3][r] = wv.w;
        }
        __syncthreads();
        #pragma unroll
        for (int k = 0; k < 32; ++k) {
            float4 a = *reinterpret_cast<const float4*>(&Xs[k][ty * 4]);
            float4 bv = *reinterpret_cast<const float4*>(&Ws[k][tx * 4]);
            float av[4] = {a.x, a.y, a.z, a.w};
            float bb[4] = {bv.x, bv.y, bv.z, bv.w};
            #pragma unroll
            for (int i = 0; i < 4; ++i)
                #pragma unroll
                for (int j = 0; j < 4; ++j)
                    acc[i][j] = fmaf(av[i], bb[j], acc[i][j]);
        }
        __syncthreads();
    }
    #pragma unroll
    for (int i = 0; i < 4; ++i) {
        int row = row0 + ty * 4 + i;
        float4 o;
        float b0 = bias ? bias[col0 + tx * 4 + 0] : 0.f;
        float b1 = bias ? bias[col0 + tx * 4 + 1] : 0.f;
        float b2 = bias ? bias[col0 + tx * 4 + 2] : 0.f;
        float b3 = bias ? bias[col0 + tx * 4 + 3] : 0.f;
        o.x = acc[i][0] + b0; o.y = acc[i][1] + b1; o.z = acc[i][2] + b2; o.w = acc[i][3] + b3;
        *reinterpret_cast<float4*>(C + (size_t)row * Nc + col0 + tx * 4) = o;
    }
}

// ---------------- agg[b,m,e,:] = sum_n bit(b,e,m,n) * msg[b,n,e,:]
// block: 32 m-rows; thread: 4 m-rows (mg) x 4 k (kseg)
__global__ __launch_bounds__(256) void agg_kernel(const unsigned* __restrict__ Abits,
                                                  const float* __restrict__ msg,
                                                  float* __restrict__ agg) {
    int b = blockIdx.z, e = blockIdx.y, m0 = blockIdx.x * 32;
    int tid = threadIdx.x;
    int kseg = tid & 31;   // 32 segs of 4 floats
    int mg = tid >> 5;     // 8 groups of 4 m rows
    __shared__ float Ms[64][HH];
    float4 acc[4] = {};
    const unsigned* abase = Abits + ((b * E1 + e) * NN + m0 + mg * 4) * 16;
    for (int n0 = 0; n0 < NN; n0 += 64) {
        #pragma unroll
        for (int q = 0; q < 8; ++q) {
            int fp = q * 256 + tid;   // float4 idx 0..2047
            int nn = fp >> 5;
            int c4 = fp & 31;
            float4 v = *reinterpret_cast<const float4*>(
                msg + ((size_t)(b * NN + n0 + nn) * E1 + e) * HH + c4 * 4);
            *reinterpret_cast<float4*>(&Ms[nn][c4 * 4]) = v;
        }
        __syncthreads();
        unsigned wrd[2][4];
        #pragma unroll
        for (int i = 0; i < 4; ++i) {
            wrd[0][i] = abase[i * 16 + (n0 >> 5)];
            wrd[1][i] = abase[i * 16 + (n0 >> 5) + 1];
        }
        #pragma unroll
        for (int half = 0; half < 2; ++half) {
            #pragma unroll 4
            for (int nn2 = 0; nn2 < 32; ++nn2) {
                int nn = half * 32 + nn2;
                float4 v = *reinterpret_cast<const float4*>(&Ms[nn][kseg * 4]);
                #pragma unroll
                for (int i = 0; i < 4; ++i) {
                    float f = (float)((wrd[half][i] >> nn2) & 1u);
                    acc[i].x = fmaf(f, v.x, acc[i].x);
                    acc[i].y = fmaf(f, v.y, acc[i].y);
                    acc[i].z = fmaf(f, v.z, acc[i].z);
                    acc[i].w = fmaf(f, v.w, acc[i].w);
                }
            }
        }
        __syncthreads();
    }
    #pragma unroll
    for (int i = 0; i < 4; ++i)
        *reinterpret_cast<float4*>(agg + ((size_t)(b * NN + m0 + mg * 4 + i) * E1 + e) * HH + kseg * 4) = acc[i];
}

// ---------------- GRU gates (gi includes bih, gh includes bhh); in-place state update
__global__ void gru_gate_kernel(const float* __restrict__ gi, const float* __restrict__ gh,
                                float* __restrict__ state) {
    int t = blockIdx.x * blockDim.x + threadIdx.x;
    if (t >= BB * NN * HH) return;
    int row = t >> 7, j = t & 127;
    const float* gir = gi + (size_t)row * 384;
    const float* ghr = gh + (size_t)row * 384;
    float ir = gir[j], iz = gir[128 + j], in_ = gir[256 + j];
    float hr = ghr[j], hz = ghr[128 + j], hn = ghr[256 + j];
    float r = 1.f / (1.f + expf(-(ir + hr)));
    float z = 1.f / (1.f + expf(-(iz + hz)));
    float n = tanhf(in_ + r * hn);
    float h = state[t];
    state[t] = (1.f - z) * n + z * h;
}

// ---------------- set2vec (3 LSTM+attention steps) + output linear; one block per graph
__global__ __launch_bounds__(256) void s2v_kernel(const float* __restrict__ state,
                                                  const float* __restrict__ wih,
                                                  const float* __restrict__ whh,
                                                  const float* __restrict__ bih,
                                                  const float* __restrict__ bhh,
                                                  const float* __restrict__ Wout,
                                                  const float* __restrict__ bout,
                                                  float* __restrict__ out) {
    int b = blockIdx.x, tid = threadIdx.x;
    __shared__ float q[2 * HH];
    __shared__ float h[HH], c[HH];
    __shared__ float g[4 * HH];
    __shared__ float att[NN];
    __shared__ float red[256];
    const float* m = state + (size_t)b * NN * HH;
    if (tid < 2 * HH) q[tid] = 0.f;
    if (tid < HH) { h[tid] = 0.f; c[tid] = 0.f; }
    __syncthreads();
    for (int step = 0; step < NS2V; ++step) {
        // g = q@wih.T + bih + h@whh.T + bhh   (512 outputs)
        for (int j = tid; j < 4 * HH; j += 256) {
            float acc = bih[j] + bhh[j];
            const float* wi = wih + (size_t)j * (2 * HH);
            #pragma unroll 4
            for (int d = 0; d < 2 * HH; ++d) acc = fmaf(q[d], wi[d], acc);
            const float* wh = whh + (size_t)j * HH;
            #pragma unroll 4
            for (int d = 0; d < HH; ++d) acc = fmaf(h[d], wh[d], acc);
            g[j] = acc;
        }
        __syncthreads();
        if (tid < HH) {
            float i_ = 1.f / (1.f + expf(-g[tid]));
            float f_ = 1.f / (1.f + expf(-g[HH + tid]));
            float g_ = tanhf(g[2 * HH + tid]);
            float o_ = 1.f / (1.f + expf(-g[3 * HH + tid]));
            float c2 = f_ * c[tid] + i_ * g_;
            c[tid] = c2;
            h[tid] = o_ * tanhf(c2);
        }
        __syncthreads();
        // attention logits att[n] = m[n,:] . h
        for (int n = tid; n < NN; n += 256) {
            const float4* mr = reinterpret_cast<const float4*>(m + (size_t)n * HH);
            float acc = 0.f;
            #pragma unroll 8
            for (int d4 = 0; d4 < HH / 4; ++d4) {
                float4 v = mr[d4];
                acc = fmaf(v.x, h[d4 * 4 + 0],
                      fmaf(v.y, h[d4 * 4 + 1],
                      fmaf(v.z, h[d4 * 4 + 2],
                      fmaf(v.w, h[d4 * 4 + 3], acc))));
            }
            att[n] = acc;
        }
        __syncthreads();
        // softmax over 512
        float lm = fmaxf(att[tid], att[tid + 256]);
        red[tid] = lm;
        __syncthreads();
        for (int s = 128; s > 0; s >>= 1) {
            if (tid < s) red[tid] = fmaxf(red[tid], red[tid + s]);
            __syncthreads();
        }
        float mx = red[0];
        __syncthreads();
        float e0 = expf(att[tid] - mx), e1 = expf(att[tid + 256] - mx);
        att[tid] = e0; att[tid + 256] = e1;
        red[tid] = e0 + e1;
        __syncthreads();
        for (int s = 128; s > 0; s >>= 1) {
            if (tid < s) red[tid] += red[tid + s];
            __syncthreads();
        }
        float inv = 1.f / red[0];
        __syncthreads();
        // read vector r[k] = (att @ m)[k] * inv ; q = [h, r]
        if (tid < HH) {
            float acc = 0.f;
            for (int n = 0; n < NN; ++n) acc = fmaf(att[n], m[(size_t)n * HH + tid], acc);
            q[tid] = h[tid];
            q[HH + tid] = acc * inv;
        }
        __syncthreads();
    }
    if (tid < DOUT) {
        float acc = bout[tid];
        const float* w = Wout + tid * (2 * HH);
        #pragma unroll 8
        for (int d = 0; d < 2 * HH; ++d) acc = fmaf(q[d], w[d], acc);
        out[b * DOUT + tid] = acc;
    }
}

extern "C" void kernel_launch(void* const* d_in, const int* in_sizes, int n_in,
                              void* d_out, int out_size, void* d_ws, size_t ws_size,
                              hipStream_t stream) {
    const int*   node_feat = (const int*)d_in[0];
    const float* L         = (const float*)d_in[1];
    const float* node_emb  = (const float*)d_in[2];
    const float* W_in      = (const float*)d_in[3];
    const float* b_in      = (const float*)d_in[4];
    const float* edge_emb  = (const float*)d_in[5];
    const float* gru_wih   = (const float*)d_in[6];
    const float* gru_whh   = (const float*)d_in[7];
    const float* gru_bih   = (const float*)d_in[8];
    const float* gru_bhh   = (const float*)d_in[9];
    const float* lstm_wih  = (const float*)d_in[10];
    const float* lstm_whh  = (const float*)d_in[11];
    const float* lstm_bih  = (const float*)d_in[12];
    const float* lstm_bhh  = (const float*)d_in[13];
    const float* W_out     = (const float*)d_in[14];
    const float* b_out     = (const float*)d_in[15];
    float* out = (float*)d_out;

    char* ws = (char*)d_ws;
    float*    state = (float*)ws;                          // 8 MiB
    unsigned* Abits = (unsigned*)(ws + (8u << 20));        // 4 MiB
    float*    buf1  = (float*)(ws + (12u << 20));          // 32 MiB : msg, then gi
    float*    buf2  = (float*)(ws + (44u << 20));          // 32 MiB : agg, then gh
    float*    Wmsg  = (float*)(ws + (76u << 20));          // 0.25 MiB

    const int M = BB * NN;   // 16384

    pack_A_kernel<<<(BB * NN * 16) / 256, 256, 0, stream>>>(L, Abits);
    transposeW_kernel<<<(E1 * HH * HH) / 256, 256, 0, stream>>>(edge_emb, Wmsg);
    embed_kernel<<<M, 128, 0, stream>>>(node_feat, node_emb, W_in, b_in, state);

    for (int p = 0; p < NPROP; ++p) {
        // msg = state @ Wmsg^T   [16384 x 512]
        gemm_kernel<128><<<dim3(512 / 64, M / 64), 256, 0, stream>>>(state, Wmsg, nullptr, buf1, 512);
        // agg = A @ msg per (b, e)
        agg_kernel<<<dim3(NN / 32, E1, BB), 256, 0, stream>>>(Abits, buf1, buf2);
        // gi = agg @ gru_wih^T + bih   [16384 x 384]
        gemm_kernel<512><<<dim3(384 / 64, M / 64), 256, 0, stream>>>(buf2, gru_wih, gru_bih, buf1, 384);
        // gh = state @ gru_whh^T + bhh [16384 x 384]
        gemm_kernel<128><<<dim3(384 / 64, M / 64), 256, 0, stream>>>(state, gru_whh, gru_bhh, buf2, 384);
        // gates -> state (in place)
        gru_gate_kernel<<<(M * HH) / 256, 256, 0, stream>>>(buf1, buf2, state);
    }

    s2v_kernel<<<BB, 256, 0, stream>>>(state, lstm_wih, lstm_whh, lstm_bih, lstm_bhh,
                                       W_out, b_out, out);
}

// Round 3
// 1062.887 us; speedup vs baseline: 1.5822x; 1.5822x over previous
//
#include <hip/hip_runtime.h>
#include <hip/hip_bf16.h>

#define BB 32
#define NN 512
#define DA 100
#define DIN 64
#define HH 128
#define E1 4
#define DOUT 16
#define NPROP 5
#define NS2V 3
#define MHALF 8192          // rows per half-batch (16 graphs)

typedef __attribute__((ext_vector_type(8))) short bf16x8;
typedef __attribute__((ext_vector_type(4))) float f32x4;
typedef __attribute__((ext_vector_type(4))) unsigned short us4;
typedef unsigned short ushort_t;

__device__ __forceinline__ unsigned short f2bf(float f) {
    __hip_bfloat16 h = __float2bfloat16(f);
    return *reinterpret_cast<unsigned short*>(&h);
}
__device__ __forceinline__ float bf2f(unsigned short u) {
    unsigned v = ((unsigned)u) << 16;
    float f;
    __builtin_memcpy(&f, &v, 4);
    return f;
}

// ---------------- pack A bits: L[b,m,n,e] != 0 -> bit n%32 of Abits[((b*E1+e)*N+m)*16 + n/32]
__global__ void pack_A_kernel(const float* __restrict__ L, unsigned* __restrict__ Abits) {
    int t = blockIdx.x * blockDim.x + threadIdx.x;   // (b, m, w)
    if (t >= BB * NN * (NN / 32)) return;
    int w = t & 15;
    int m = (t >> 4) & (NN - 1);
    int b = t >> (4 + 9);
    const float* src = L + ((size_t)(b * NN + m) * NN + 32 * w) * E1;
    unsigned bits[E1] = {0u, 0u, 0u, 0u};
    #pragma unroll 8
    for (int j = 0; j < 32; ++j) {
        float4 v = *reinterpret_cast<const float4*>(src + j * 4);
        if (v.x != 0.f) bits[0] |= (1u << j);
        if (v.y != 0.f) bits[1] |= (1u << j);
        if (v.z != 0.f) bits[2] |= (1u << j);
        if (v.w != 0.f) bits[3] |= (1u << j);
    }
    #pragma unroll
    for (int e = 0; e < E1; ++e)
        Abits[((b * E1 + e) * NN + m) * 16 + w] = bits[e];
}

// ---------------- convert weights to split bf16 (hi + residual lo)
// Wmsg[(e*H+k)*H + h] = edge_emb[e, h*H + k]  (transposed to Linear layout)
__global__ void convW_kernel(const float* __restrict__ EE, const float* __restrict__ wih,
                             const float* __restrict__ whh,
                             ushort_t* __restrict__ Wm_h, ushort_t* __restrict__ Wm_l,
                             ushort_t* __restrict__ wih_h, ushort_t* __restrict__ wih_l,
                             ushort_t* __restrict__ whh_h, ushort_t* __restrict__ whh_l) {
    int t = blockIdx.x * blockDim.x + threadIdx.x;
    float v; ushort_t *ph, *pl; int idx;
    if (t < E1 * HH * HH) {
        int h = t & (HH - 1);
        int k = (t >> 7) & (HH - 1);
        int e = t >> 14;
        v = EE[e * HH * HH + h * HH + k];
        ph = Wm_h; pl = Wm_l; idx = t;
    } else if (t < E1 * HH * HH + 384 * 512) {
        idx = t - E1 * HH * HH;
        v = wih[idx]; ph = wih_h; pl = wih_l;
    } else if (t < E1 * HH * HH + 384 * 512 + 384 * 128) {
        idx = t - E1 * HH * HH - 384 * 512;
        v = whh[idx]; ph = whh_h; pl = whh_l;
    } else return;
    unsigned short hi = f2bf(v);
    ph[idx] = hi;
    pl[idx] = f2bf(v - bf2f(hi));
}

// ---------------- embed: state[row, h] = node_emb[nf[row]] . W_in[h,:] + b_in[h] -> split planes
__global__ void embed_kernel(const int* __restrict__ nf, const float* __restrict__ emb,
                             const float* __restrict__ Win, const float* __restrict__ bin,
                             ushort_t* __restrict__ s_hi, ushort_t* __restrict__ s_lo) {
    int row = blockIdx.x;
    int h = threadIdx.x;
    __shared__ float e[DIN];
    int a = nf[row];
    if (h < DIN) e[h] = emb[a * DIN + h];
    __syncthreads();
    float acc = bin[h];
    const float* w = Win + h * DIN;
    #pragma unroll
    for (int d = 0; d < DIN; ++d) acc = fmaf(e[d], w[d], acc);
    unsigned short hi = f2bf(acc);
    s_hi[row * HH + h] = hi;
    s_lo[row * HH + h] = f2bf(acc - bf2f(hi));
}

// ---------------- split-bf16 MFMA GEMM: C[M x N] = X[M x K] @ W[N x K]^T
// BM=128, BN=64, BK=32, 256 threads = 4 waves (2x2), per-wave 64x32 (4x2 16x16 frags)
// X always split (hi plane at X, lo at X+xplane). W split iff WSPLIT; WBITS expands 0/1 bits (exact).
// MODE 1: split bf16 transposed store out[col*ldo+row] (hi/lo planes, oplane apart), no bias
// MODE 3: fp32 normal store out[row*ldo+col] + bias
template <int MODE, bool AGG, bool WBITS, int K, bool WSPLIT>
__global__ __launch_bounds__(256) void mm_kernel(const ushort_t* __restrict__ X, size_t xplane,
                                                 const void* __restrict__ Wp, size_t wplane,
                                                 const float* __restrict__ bias,
                                                 void* __restrict__ outv, size_t oplane,
                                                 int ldx, int ldw, int ldo) {
    __shared__ __align__(16) ushort_t Xs[2][128 * 40];
    __shared__ __align__(16) ushort_t Ws[2][64 * 40];
    int tid = threadIdx.x;
    int row0 = blockIdx.y * 128, col0 = blockIdx.x * 64;
    const ushort_t* W = (const ushort_t*)Wp;
    const unsigned* Wb = (const unsigned*)Wp;
    size_t out_off = 0;
    if constexpr (AGG) {
        int e = blockIdx.z & 3, b = blockIdx.z >> 2;
        X += (size_t)e * HH * ldx + (size_t)b * NN;      // msgT slice [128 h][...], k index = n
        Wb += (size_t)blockIdx.z * NN * 16;              // A bits for (b_local, e)
        out_off = (size_t)b * NN * NN + (size_t)e * HH;  // agg[(b*512+m)*512 + e*128 + k]
    }
    int lane = tid & 63;
    int wave = tid >> 6;
    int wm = wave & 1, wn = wave >> 1;
    int r16 = lane & 15, kg = lane >> 4;

    f32x4 acc[4][2] = {};

    for (int k0 = 0; k0 < K; k0 += 32) {
        bf16x8 xh[2], xl[2];
        #pragma unroll
        for (int q = 0; q < 2; ++q) {
            int chunk = q * 256 + tid;
            int r = chunk >> 2, kc = chunk & 3;
            const ushort_t* xp = X + (size_t)(row0 + r) * ldx + k0 + kc * 8;
            xh[q] = *reinterpret_cast<const bf16x8*>(xp);
            xl[q] = *reinterpret_cast<const bf16x8*>(xp + xplane);
        }
        bf16x8 wh, wl;
        if constexpr (WBITS) {
            int m = tid >> 2, byteq = tid & 3;
            unsigned word = Wb[(size_t)(col0 + m) * 16 + (k0 >> 5)];
            #pragma unroll
            for (int j = 0; j < 8; ++j)
                wh[j] = (short)(((word >> (byteq * 8 + j)) & 1u) ? 0x3F80 : 0);
        } else {
            int r = tid >> 2, kc = tid & 3;
            const ushort_t* wp2 = W + (size_t)(col0 + r) * ldw + k0 + kc * 8;
            wh = *reinterpret_cast<const bf16x8*>(wp2);
            if constexpr (WSPLIT) wl = *reinterpret_cast<const bf16x8*>(wp2 + wplane);
        }
        __syncthreads();
        #pragma unroll
        for (int q = 0; q < 2; ++q) {
            int chunk = q * 256 + tid;
            int r = chunk >> 2, kc = chunk & 3;
            *reinterpret_cast<bf16x8*>(&Xs[0][r * 40 + kc * 8]) = xh[q];
            *reinterpret_cast<bf16x8*>(&Xs[1][r * 40 + kc * 8]) = xl[q];
        }
        {
            int r = tid >> 2, kc = tid & 3;   // for WBITS: r=m, kc=byteq — same offsets
            *reinterpret_cast<bf16x8*>(&Ws[0][r * 40 + kc * 8]) = wh;
            if constexpr (WSPLIT)
                *reinterpret_cast<bf16x8*>(&Ws[1][r * 40 + kc * 8]) = wl;
        }
        __syncthreads();
        bf16x8 af_h[4], af_l[4], bf_h[2], bf_l[2];
        #pragma unroll
        for (int mi = 0; mi < 4; ++mi) {
            af_h[mi] = *reinterpret_cast<const bf16x8*>(&Xs[0][(wm * 64 + mi * 16 + r16) * 40 + kg * 8]);
            af_l[mi] = *reinterpret_cast<const bf16x8*>(&Xs[1][(wm * 64 + mi * 16 + r16) * 40 + kg * 8]);
        }
        #pragma unroll
        for (int ni = 0; ni < 2; ++ni) {
            bf_h[ni] = *reinterpret_cast<const bf16x8*>(&Ws[0][(wn * 32 + ni * 16 + r16) * 40 + kg * 8]);
            if constexpr (WSPLIT)
                bf_l[ni] = *reinterpret_cast<const bf16x8*>(&Ws[1][(wn * 32 + ni * 16 + r16) * 40 + kg * 8]);
        }
        #pragma unroll
        for (int mi = 0; mi < 4; ++mi)
            #pragma unroll
            for (int ni = 0; ni < 2; ++ni) {
                acc[mi][ni] = __builtin_amdgcn_mfma_f32_16x16x32_bf16(af_h[mi], bf_h[ni], acc[mi][ni], 0, 0, 0);
                acc[mi][ni] = __builtin_amdgcn_mfma_f32_16x16x32_bf16(af_l[mi], bf_h[ni], acc[mi][ni], 0, 0, 0);
                if constexpr (WSPLIT)
                    acc[mi][ni] = __builtin_amdgcn_mfma_f32_16x16x32_bf16(af_h[mi], bf_l[ni], acc[mi][ni], 0, 0, 0);
            }
    }

    if constexpr (MODE == 1) {
        ushort_t* out = (ushort_t*)outv + out_off;
        #pragma unroll
        for (int mi = 0; mi < 4; ++mi) {
            int rowb = row0 + wm * 64 + mi * 16 + kg * 4;
            #pragma unroll
            for (int ni = 0; ni < 2; ++ni) {
                int col = col0 + wn * 32 + ni * 16 + r16;
                us4 oh, ol;
                #pragma unroll
                for (int j = 0; j < 4; ++j) {
                    float v = acc[mi][ni][j];
                    unsigned short hv = f2bf(v);
                    oh[j] = hv;
                    ol[j] = f2bf(v - bf2f(hv));
                }
                *reinterpret_cast<us4*>(&out[(size_t)col * ldo + rowb]) = oh;
                *reinterpret_cast<us4*>(&out[oplane + (size_t)col * ldo + rowb]) = ol;
            }
        }
    } else {
        float* out = (float*)outv;
        #pragma unroll
        for (int ni = 0; ni < 2; ++ni) {
            int col = col0 + wn * 32 + ni * 16 + r16;
            float bv = bias[col];
            #pragma unroll
            for (int mi = 0; mi < 4; ++mi) {
                int rowb = row0 + wm * 64 + mi * 16 + kg * 4;
                #pragma unroll
                for (int j = 0; j < 4; ++j)
                    out[(size_t)(rowb + j) * ldo + col] = acc[mi][ni][j] + bv;
            }
        }
    }
}

// ---------------- GRU gates from fp32 gi/gh; updates split state planes (half-local rows)
__global__ void gru_gate_kernel(const float* __restrict__ gi, const float* __restrict__ gh,
                                ushort_t* __restrict__ s_hi, ushort_t* __restrict__ s_lo,
                                size_t half_off) {
    int t = blockIdx.x * blockDim.x + threadIdx.x;
    if (t >= MHALF * HH) return;
    int row = t >> 7, j = t & 127;
    const float* gir = gi + (size_t)row * 384;
    const float* ghr = gh + (size_t)row * 384;
    float ir = gir[j], iz = gir[128 + j], in_ = gir[256 + j];
    float hr = ghr[j], hz = ghr[128 + j], hn = ghr[256 + j];
    float r = 1.f / (1.f + expf(-(ir + hr)));
    float z = 1.f / (1.f + expf(-(iz + hz)));
    float n = tanhf(in_ + r * hn);
    size_t g = half_off + (size_t)t;
    float h = bf2f(s_hi[g]) + bf2f(s_lo[g]);
    float v = (1.f - z) * n + z * h;
    unsigned short hv = f2bf(v);
    s_hi[g] = hv;
    s_lo[g] = f2bf(v - bf2f(hv));
}

// ---------------- set2vec (3 LSTM+attention steps) + output linear; one block per graph
__global__ __launch_bounds__(256) void s2v_kernel(const ushort_t* __restrict__ s_hi,
                                                  const ushort_t* __restrict__ s_lo,
                                                  const float* __restrict__ wih,
                                                  const float* __restrict__ whh,
                                                  const float* __restrict__ bih,
                                                  const float* __restrict__ bhh,
                                                  const float* __restrict__ Wout,
                                                  const float* __restrict__ bout,
                                                  float* __restrict__ out) {
    int b = blockIdx.x, tid = threadIdx.x;
    __shared__ float q[2 * HH];
    __shared__ float h[HH], c[HH];
    __shared__ float g[4 * HH];
    __shared__ float att[NN];
    __shared__ float red[256];
    const ushort_t* mh = s_hi + (size_t)b * NN * HH;
    const ushort_t* ml = s_lo + (size_t)b * NN * HH;
    if (tid < 2 * HH) q[tid] = 0.f;
    if (tid < HH) { h[tid] = 0.f; c[tid] = 0.f; }
    __syncthreads();
    for (int step = 0; step < NS2V; ++step) {
        for (int j = tid; j < 4 * HH; j += 256) {
            float acc = bih[j] + bhh[j];
            const float* wi = wih + (size_t)j * (2 * HH);
            #pragma unroll 4
            for (int d = 0; d < 2 * HH; ++d) acc = fmaf(q[d], wi[d], acc);
            const float* wh = whh + (size_t)j * HH;
            #pragma unroll 4
            for (int d = 0; d < HH; ++d) acc = fmaf(h[d], wh[d], acc);
            g[j] = acc;
        }
        __syncthreads();
        if (tid < HH) {
            float i_ = 1.f / (1.f + expf(-g[tid]));
            float f_ = 1.f / (1.f + expf(-g[HH + tid]));
            float g_ = tanhf(g[2 * HH + tid]);
            float o_ = 1.f / (1.f + expf(-g[3 * HH + tid]));
            float c2 = f_ * c[tid] + i_ * g_;
            c[tid] = c2;
            h[tid] = o_ * tanhf(c2);
        }
        __syncthreads();
        for (int n = tid; n < NN; n += 256) {
            const us4* vh4 = reinterpret_cast<const us4*>(mh + (size_t)n * HH);
            const us4* vl4 = reinterpret_cast<const us4*>(ml + (size_t)n * HH);
            float acc = 0.f;
            #pragma unroll 8
            for (int d4 = 0; d4 < HH / 4; ++d4) {
                us4 a = vh4[d4], l = vl4[d4];
                #pragma unroll
                for (int j = 0; j < 4; ++j)
                    acc = fmaf(bf2f(a[j]) + bf2f(l[j]), h[d4 * 4 + j], acc);
            }
            att[n] = acc;
        }
        __syncthreads();
        float lm = fmaxf(att[tid], att[tid + 256]);
        red[tid] = lm;
        __syncthreads();
        for (int s = 128; s > 0; s >>= 1) {
            if (tid < s) red[tid] = fmaxf(red[tid], red[tid + s]);
            __syncthreads();
        }
        float mx = red[0];
        __syncthreads();
        float e0 = expf(att[tid] - mx), e1 = expf(att[tid + 256] - mx);
        att[tid] = e0; att[tid + 256] = e1;
        red[tid] = e0 + e1;
        __syncthreads();
        for (int s = 128; s > 0; s >>= 1) {
            if (tid < s) red[tid] += red[tid + s];
            __syncthreads();
        }
        float inv = 1.f / red[0];
        __syncthreads();
        if (tid < HH) {
            float acc = 0.f;
            for (int n = 0; n < NN; ++n)
                acc = fmaf(att[n], bf2f(mh[(size_t)n * HH + tid]) + bf2f(ml[(size_t)n * HH + tid]), acc);
            q[tid] = h[tid];
            q[HH + tid] = acc * inv;
        }
        __syncthreads();
    }
    if (tid < DOUT) {
        float acc = bout[tid];
        const float* w = Wout + tid * (2 * HH);
        #pragma unroll 8
        for (int d = 0; d < 2 * HH; ++d) acc = fmaf(q[d], w[d], acc);
        out[b * DOUT + tid] = acc;
    }
}

extern "C" void kernel_launch(void* const* d_in, const int* in_sizes, int n_in,
                              void* d_out, int out_size, void* d_ws, size_t ws_size,
                              hipStream_t stream) {
    const int*   node_feat = (const int*)d_in[0];
    const float* L         = (const float*)d_in[1];
    const float* node_emb  = (const float*)d_in[2];
    const float* W_in      = (const float*)d_in[3];
    const float* b_in      = (const float*)d_in[4];
    const float* edge_emb  = (const float*)d_in[5];
    const float* gru_wih   = (const float*)d_in[6];
    const float* gru_whh   = (const float*)d_in[7];
    const float* gru_bih   = (const float*)d_in[8];
    const float* gru_bhh   = (const float*)d_in[9];
    const float* lstm_wih  = (const float*)d_in[10];
    const float* lstm_whh  = (const float*)d_in[11];
    const float* lstm_bih  = (const float*)d_in[12];
    const float* lstm_bhh  = (const float*)d_in[13];
    const float* W_out     = (const float*)d_in[14];
    const float* b_out     = (const float*)d_in[15];
    float* out = (float*)d_out;

    char* ws = (char*)d_ws;
    // layout (MiB): 0 state_hi(4) | 4 state_lo(4) | 8 Abits(4) | 12 msgT_hi(8) | 20 msgT_lo(8)
    //               28 agg_hi(8) | 36 agg_lo(8) | 44 gi f32(12) | 56 gh f32(12) | 68 weights(~1.2)
    ushort_t* state_hi = (ushort_t*)ws;
    ushort_t* state_lo = (ushort_t*)(ws + (4u << 20));
    unsigned* Abits    = (unsigned*)(ws + (8u << 20));
    ushort_t* msgT_hi  = (ushort_t*)(ws + (12u << 20));
    ushort_t* agg_hi   = (ushort_t*)(ws + (28u << 20));
    float*    gi       = (float*)(ws + (44u << 20));
    float*    gh       = (float*)(ws + (56u << 20));
    ushort_t* Wm_h     = (ushort_t*)(ws + (68u << 20));
    ushort_t* Wm_l     = Wm_h + 65536;
    ushort_t* wih_h    = Wm_l + 65536;
    ushort_t* wih_l    = wih_h + 196608;
    ushort_t* whh_h    = wih_l + 196608;
    ushort_t* whh_l    = whh_h + 49152;

    const size_t SPLANE = 2097152;    // state plane stride (elems)
    const size_t MPLANE = 4194304;    // msgT plane stride
    const size_t APLANE = 4194304;    // agg plane stride

    pack_A_kernel<<<(BB * NN * 16) / 256, 256, 0, stream>>>(L, Abits);
    convW_kernel<<<(E1 * HH * HH + 384 * 512 + 384 * 128 + 255) / 256, 256, 0, stream>>>(
        edge_emb, gru_wih, gru_whh, Wm_h, Wm_l, wih_h, wih_l, whh_h, whh_l);
    embed_kernel<<<BB * NN, 128, 0, stream>>>(node_feat, node_emb, W_in, b_in, state_hi, state_lo);

    for (int half = 0; half < 2; ++half) {
        const ushort_t* Xst = state_hi + (size_t)half * MHALF * HH;
        const unsigned* Ab  = Abits + (size_t)half * 16 * E1 * NN * 16;
        size_t half_off = (size_t)half * MHALF * HH;
        for (int p = 0; p < NPROP; ++p) {
            // msgT[(e*128+k)][8192 rows] = (state @ Wmsg^T)^T : M=8192, N=512, K=128 (X,W split)
            mm_kernel<1, false, false, 128, true><<<dim3(8, 64), 256, 0, stream>>>(
                Xst, SPLANE, Wm_h, 65536, nullptr, msgT_hi, MPLANE, 128, 128, MHALF);
            // agg: per (b_local,e): C'[k][m] = msgT_slice @ Abits^T : M=128, N=512, K=512 (A exact)
            mm_kernel<1, true, true, 512, false><<<dim3(8, 1, 64), 256, 0, stream>>>(
                msgT_hi, MPLANE, Ab, 0, nullptr, agg_hi, APLANE, MHALF, 0, 512);
            // gi = agg @ wih^T + bih : M=8192, N=384, K=512 -> fp32
            mm_kernel<3, false, false, 512, true><<<dim3(6, 64), 256, 0, stream>>>(
                agg_hi, APLANE, wih_h, 196608, gru_bih, gi, 0, 512, 512, 384);
            // gh = state @ whh^T + bhh : M=8192, N=384, K=128 -> fp32
            mm_kernel<3, false, false, 128, true><<<dim3(6, 64), 256, 0, stream>>>(
                Xst, SPLANE, whh_h, 49152, gru_bhh, gh, 0, 128, 128, 384);
            // gates -> state planes
            gru_gate_kernel<<<(MHALF * HH) / 256, 256, 0, stream>>>(gi, gh, state_hi, state_lo, half_off);
        }
    }

    s2v_kernel<<<BB, 256, 0, stream>>>(state_hi, state_lo, lstm_wih, lstm_whh,
                                       lstm_bih, lstm_bhh, W_out, b_out, out);
}

// Round 4
// 848.750 us; speedup vs baseline: 1.9814x; 1.2523x over previous
//
#include <hip/hip_runtime.h>
#include <hip/hip_bf16.h>

#define BB 32
#define NN 512
#define DA 100
#define DIN 64
#define HH 128
#define E1 4
#define DOUT 16
#define NPROP 5
#define NS2V 3
#define MHALF 8192          // rows per half-batch (16 graphs)

typedef __attribute__((ext_vector_type(8))) short bf16x8;
typedef __attribute__((ext_vector_type(4))) float f32x4;
typedef __attribute__((ext_vector_type(4))) unsigned short us4;
typedef __attribute__((ext_vector_type(8))) unsigned short us8;
typedef unsigned short ushort_t;

__device__ __forceinline__ unsigned short f2bf(float f) {
    __hip_bfloat16 h = __float2bfloat16(f);
    return *reinterpret_cast<unsigned short*>(&h);
}
__device__ __forceinline__ float bf2f(unsigned short u) {
    unsigned v = ((unsigned)u) << 16;
    float f;
    __builtin_memcpy(&f, &v, 4);
    return f;
}

// ---------------- pack A bits: L[b,m,n,e] != 0 -> bit n%32 of Abits[((b*E1+e)*N+m)*16 + n/32]
__global__ void pack_A_kernel(const float* __restrict__ L, unsigned* __restrict__ Abits) {
    int t = blockIdx.x * blockDim.x + threadIdx.x;   // (b, m, w)
    if (t >= BB * NN * (NN / 32)) return;
    int w = t & 15;
    int m = (t >> 4) & (NN - 1);
    int b = t >> (4 + 9);
    const float* src = L + ((size_t)(b * NN + m) * NN + 32 * w) * E1;
    unsigned bits[E1] = {0u, 0u, 0u, 0u};
    #pragma unroll 8
    for (int j = 0; j < 32; ++j) {
        float4 v = *reinterpret_cast<const float4*>(src + j * 4);
        if (v.x != 0.f) bits[0] |= (1u << j);
        if (v.y != 0.f) bits[1] |= (1u << j);
        if (v.z != 0.f) bits[2] |= (1u << j);
        if (v.w != 0.f) bits[3] |= (1u << j);
    }
    #pragma unroll
    for (int e = 0; e < E1; ++e)
        Abits[((b * E1 + e) * NN + m) * 16 + w] = bits[e];
}

// ---------------- fused-weight precompute:
// U[j, e*128+h] = sum_k wih[j, e*128+k] * edge_emb[e, h*128+k]   (fp32, then split bf16)
// whh split bf16
__global__ void convW_kernel(const float* __restrict__ EE, const float* __restrict__ wih,
                             const float* __restrict__ whh,
                             ushort_t* __restrict__ U_h, ushort_t* __restrict__ U_l,
                             ushort_t* __restrict__ whh_h, ushort_t* __restrict__ whh_l) {
    int t = blockIdx.x * blockDim.x + threadIdx.x;
    if (t < 384 * 512) {
        int col = t & 511;
        int j = t >> 9;
        int e = col >> 7, h = col & 127;
        const float4* wp = reinterpret_cast<const float4*>(wih + (size_t)j * 512 + e * 128);
        const float4* ep = reinterpret_cast<const float4*>(EE + (size_t)e * 16384 + h * 128);
        float acc = 0.f;
        #pragma unroll 8
        for (int k4 = 0; k4 < 32; ++k4) {
            float4 a = wp[k4], b = ep[k4];
            acc = fmaf(a.x, b.x, fmaf(a.y, b.y, fmaf(a.z, b.z, fmaf(a.w, b.w, acc))));
        }
        unsigned short hi = f2bf(acc);
        U_h[t] = hi;
        U_l[t] = f2bf(acc - bf2f(hi));
        return;
    }
    int t2 = t - 384 * 512;
    if (t2 < 384 * 128) {
        float v = whh[t2];
        unsigned short hi = f2bf(v);
        whh_h[t2] = hi;
        whh_l[t2] = f2bf(v - bf2f(hi));
    }
}

// ---------------- embed: state[row, h] = node_emb[nf[row]] . W_in[h,:] + b_in[h] -> split planes
__global__ void embed_kernel(const int* __restrict__ nf, const float* __restrict__ emb,
                             const float* __restrict__ Win, const float* __restrict__ bin,
                             ushort_t* __restrict__ s_hi, ushort_t* __restrict__ s_lo) {
    int row = blockIdx.x;
    int h = threadIdx.x;
    __shared__ float e[DIN];
    int a = nf[row];
    if (h < DIN) e[h] = emb[a * DIN + h];
    __syncthreads();
    float acc = bin[h];
    const float* w = Win + h * DIN;
    #pragma unroll
    for (int d = 0; d < DIN; ++d) acc = fmaf(e[d], w[d], acc);
    unsigned short hi = f2bf(acc);
    s_hi[row * HH + h] = hi;
    s_lo[row * HH + h] = f2bf(acc - bf2f(hi));
}

// ---------------- transpose state planes: [16384][128] -> [128][16384]
__global__ __launch_bounds__(256) void transpose_kernel(const ushort_t* __restrict__ src,
                                                        ushort_t* __restrict__ dst,
                                                        size_t splane) {
    __shared__ __align__(16) ushort_t tile[128][72];
    int row0 = blockIdx.x * 64;
    int tid = threadIdx.x;
    #pragma unroll
    for (int pl = 0; pl < 2; ++pl) {
        const ushort_t* s = src + pl * splane;
        ushort_t* d = dst + pl * splane;
        #pragma unroll
        for (int q = 0; q < 4; ++q) {
            int idx = q * 256 + tid;
            int r = idx >> 4, h8 = idx & 15;
            bf16x8 v = *reinterpret_cast<const bf16x8*>(s + (size_t)(row0 + r) * HH + h8 * 8);
            #pragma unroll
            for (int j = 0; j < 8; ++j) tile[h8 * 8 + j][r] = (ushort_t)v[j];
        }
        __syncthreads();
        {
            int h = tid >> 1, rseg = (tid & 1) * 32;
            #pragma unroll
            for (int s8 = 0; s8 < 4; ++s8) {
                us8 v = *reinterpret_cast<const us8*>(&tile[h][rseg + s8 * 8]);
                *reinterpret_cast<us8*>(&d[(size_t)h * 16384 + row0 + rseg + s8 * 8]) = v;
            }
        }
        __syncthreads();
    }
}

// ---------------- split-bf16 MFMA GEMM: C[M x N] = X[M x K] @ W[N x K]^T
// BM=128, BN=64, BK=32, 256 threads = 4 waves (2x2), per-wave 64x32 (4x2 16x16 frags)
// XBITS: X tile expanded from packed 0/1 bits (exact, single plane).
// XSPLIT: X has hi/lo planes (xplane apart). WSPLIT: W has hi/lo planes.
// MODE 3: fp32 normal store out[row*ldo+col] + bias
// MODE 4: split-bf16 normal store (planes oplane apart), no bias
// AGG: per-z (b_local,e) operand offsets for the S2 = A @ state GEMM.
template <int MODE, bool AGG, bool XBITS, int K, bool XSPLIT, bool WSPLIT>
__global__ __launch_bounds__(256) void mm_kernel(const void* __restrict__ Xp, size_t xplane,
                                                 const ushort_t* __restrict__ W, size_t wplane,
                                                 const float* __restrict__ bias,
                                                 void* __restrict__ outv, size_t oplane,
                                                 int ldx, int ldw, int ldo) {
    __shared__ __align__(16) ushort_t Xs[2][128 * 40];
    __shared__ __align__(16) ushort_t Ws[2][64 * 40];
    int tid = threadIdx.x;
    int row0 = blockIdx.y * 128, col0 = blockIdx.x * 64;
    const ushort_t* X = (const ushort_t*)Xp;
    const unsigned* Xb = (const unsigned*)Xp;
    size_t out_off = 0;
    int wko = 0;
    if constexpr (AGG) {
        int e = blockIdx.z & 3, bl = blockIdx.z >> 2;
        Xb += (size_t)blockIdx.z * NN * 16;               // A bits for (b_local, e)
        wko = bl * NN;                                    // stateT column offset (n base)
        out_off = (size_t)bl * NN * NN + (size_t)e * HH;  // S2cat[(bl*512+m)*512 + e*128 + h]
    }
    int lane = tid & 63;
    int wave = tid >> 6;
    int wm = wave & 1, wn = wave >> 1;
    int r16 = lane & 15, kg = lane >> 4;

    f32x4 acc[4][2] = {};

    for (int k0 = 0; k0 < K; k0 += 32) {
        bf16x8 xh[2], xl[2];
        unsigned xword;
        if constexpr (XBITS) {
            int m = tid >> 1;
            xword = Xb[(size_t)(row0 + m) * 16 + (k0 >> 5)];
        } else {
            #pragma unroll
            for (int q = 0; q < 2; ++q) {
                int chunk = q * 256 + tid;
                int r = chunk >> 2, kc = chunk & 3;
                const ushort_t* xp = X + (size_t)(row0 + r) * ldx + k0 + kc * 8;
                xh[q] = *reinterpret_cast<const bf16x8*>(xp);
                if constexpr (XSPLIT) xl[q] = *reinterpret_cast<const bf16x8*>(xp + xplane);
            }
        }
        bf16x8 wh, wl;
        {
            int r = tid >> 2, kc = tid & 3;
            const ushort_t* wp2 = W + (size_t)(col0 + r) * ldw + wko + k0 + kc * 8;
            wh = *reinterpret_cast<const bf16x8*>(wp2);
            if constexpr (WSPLIT) wl = *reinterpret_cast<const bf16x8*>(wp2 + wplane);
        }
        __syncthreads();
        if constexpr (XBITS) {
            int m = tid >> 1, sel = tid & 1;
            #pragma unroll
            for (int j8 = 0; j8 < 2; ++j8) {
                bf16x8 xv;
                #pragma unroll
                for (int j = 0; j < 8; ++j)
                    xv[j] = (short)(((xword >> (sel * 16 + j8 * 8 + j)) & 1u) ? 0x3F80 : 0);
                *reinterpret_cast<bf16x8*>(&Xs[0][m * 40 + sel * 16 + j8 * 8]) = xv;
            }
        } else {
            #pragma unroll
            for (int q = 0; q < 2; ++q) {
                int chunk = q * 256 + tid;
                int r = chunk >> 2, kc = chunk & 3;
                *reinterpret_cast<bf16x8*>(&Xs[0][r * 40 + kc * 8]) = xh[q];
                if constexpr (XSPLIT)
                    *reinterpret_cast<bf16x8*>(&Xs[1][r * 40 + kc * 8]) = xl[q];
            }
        }
        {
            int r = tid >> 2, kc = tid & 3;
            *reinterpret_cast<bf16x8*>(&Ws[0][r * 40 + kc * 8]) = wh;
            if constexpr (WSPLIT)
                *reinterpret_cast<bf16x8*>(&Ws[1][r * 40 + kc * 8]) = wl;
        }
        __syncthreads();
        bf16x8 af_h[4], af_l[4], bf_h[2], bf_l[2];
        #pragma unroll
        for (int mi = 0; mi < 4; ++mi) {
            af_h[mi] = *reinterpret_cast<const bf16x8*>(&Xs[0][(wm * 64 + mi * 16 + r16) * 40 + kg * 8]);
            if constexpr (XSPLIT)
                af_l[mi] = *reinterpret_cast<const bf16x8*>(&Xs[1][(wm * 64 + mi * 16 + r16) * 40 + kg * 8]);
        }
        #pragma unroll
        for (int ni = 0; ni < 2; ++ni) {
            bf_h[ni] = *reinterpret_cast<const bf16x8*>(&Ws[0][(wn * 32 + ni * 16 + r16) * 40 + kg * 8]);
            if constexpr (WSPLIT)
                bf_l[ni] = *reinterpret_cast<const bf16x8*>(&Ws[1][(wn * 32 + ni * 16 + r16) * 40 + kg * 8]);
        }
        #pragma unroll
        for (int mi = 0; mi < 4; ++mi)
            #pragma unroll
            for (int ni = 0; ni < 2; ++ni) {
                acc[mi][ni] = __builtin_amdgcn_mfma_f32_16x16x32_bf16(af_h[mi], bf_h[ni], acc[mi][ni], 0, 0, 0);
                if constexpr (XSPLIT)
                    acc[mi][ni] = __builtin_amdgcn_mfma_f32_16x16x32_bf16(af_l[mi], bf_h[ni], acc[mi][ni], 0, 0, 0);
                if constexpr (WSPLIT)
                    acc[mi][ni] = __builtin_amdgcn_mfma_f32_16x16x32_bf16(af_h[mi], bf_l[ni], acc[mi][ni], 0, 0, 0);
            }
    }

    if constexpr (MODE == 3) {
        float* out = (float*)outv;
        #pragma unroll
        for (int ni = 0; ni < 2; ++ni) {
            int col = col0 + wn * 32 + ni * 16 + r16;
            float bv = bias[col];
            #pragma unroll
            for (int mi = 0; mi < 4; ++mi) {
                int rowb = row0 + wm * 64 + mi * 16 + kg * 4;
                #pragma unroll
                for (int j = 0; j < 4; ++j)
                    out[(size_t)(rowb + j) * ldo + col] = acc[mi][ni][j] + bv;
            }
        }
    } else {
        ushort_t* out = (ushort_t*)outv + out_off;
        #pragma unroll
        for (int ni = 0; ni < 2; ++ni) {
            int col = col0 + wn * 32 + ni * 16 + r16;
            #pragma unroll
            for (int mi = 0; mi < 4; ++mi) {
                int rowb = row0 + wm * 64 + mi * 16 + kg * 4;
                #pragma unroll
                for (int j = 0; j < 4; ++j) {
                    float v = acc[mi][ni][j];
                    unsigned short hv = f2bf(v);
                    out[(size_t)(rowb + j) * ldo + col] = hv;
                    out[oplane + (size_t)(rowb + j) * ldo + col] = f2bf(v - bf2f(hv));
                }
            }
        }
    }
}

// ---------------- GRU gates from fp32 gi/gh; updates split state planes (half-local rows)
__global__ void gru_gate_kernel(const float* __restrict__ gi, const float* __restrict__ gh,
                                ushort_t* __restrict__ s_hi, ushort_t* __restrict__ s_lo,
                                size_t half_off) {
    int t = blockIdx.x * blockDim.x + threadIdx.x;
    if (t >= MHALF * HH) return;
    int row = t >> 7, j = t & 127;
    const float* gir = gi + (size_t)row * 384;
    const float* ghr = gh + (size_t)row * 384;
    float ir = gir[j], iz = gir[128 + j], in_ = gir[256 + j];
    float hr = ghr[j], hz = ghr[128 + j], hn = ghr[256 + j];
    float r = 1.f / (1.f + expf(-(ir + hr)));
    float z = 1.f / (1.f + expf(-(iz + hz)));
    float n = tanhf(in_ + r * hn);
    size_t g = half_off + (size_t)t;
    float h = bf2f(s_hi[g]) + bf2f(s_lo[g]);
    float v = (1.f - z) * n + z * h;
    unsigned short hv = f2bf(v);
    s_hi[g] = hv;
    s_lo[g] = f2bf(v - bf2f(hv));
}

// ---------------- set2vec: one block per graph, 512 threads, fully parallel phases
__global__ __launch_bounds__(512) void s2v_kernel(const ushort_t* __restrict__ s_hi,
                                                  const ushort_t* __restrict__ s_lo,
                                                  const float* __restrict__ wih,
                                                  const float* __restrict__ whh,
                                                  const float* __restrict__ bih,
                                                  const float* __restrict__ bhh,
                                                  const float* __restrict__ Wout,
                                                  const float* __restrict__ bout,
                                                  float* __restrict__ out) {
    int b = blockIdx.x, tid = threadIdx.x;
    __shared__ float q[2 * HH];
    __shared__ float hs[HH], cs[HH];
    __shared__ float att[NN];
    __shared__ float red[NN];
    const ushort_t* mh = s_hi + (size_t)b * NN * HH;
    const ushort_t* ml = s_lo + (size_t)b * NN * HH;
    if (tid < 2 * HH) q[tid] = 0.f;
    if (tid < HH) { hs[tid] = 0.f; cs[tid] = 0.f; }
    __syncthreads();
    for (int step = 0; step < NS2V; ++step) {
        // ---- g[j] for j = tid (512 outputs)
        {
            float acc = bih[tid] + bhh[tid];
            const float4* wi = reinterpret_cast<const float4*>(wih + (size_t)tid * 256);
            #pragma unroll 8
            for (int d4 = 0; d4 < 64; ++d4) {
                float4 w = wi[d4];
                acc = fmaf(q[d4 * 4 + 0], w.x, fmaf(q[d4 * 4 + 1], w.y,
                      fmaf(q[d4 * 4 + 2], w.z, fmaf(q[d4 * 4 + 3], w.w, acc))));
            }
            const float4* wp = reinterpret_cast<const float4*>(whh + (size_t)tid * 128);
            #pragma unroll 8
            for (int d4 = 0; d4 < 32; ++d4) {
                float4 w = wp[d4];
                acc = fmaf(hs[d4 * 4 + 0], w.x, fmaf(hs[d4 * 4 + 1], w.y,
                      fmaf(hs[d4 * 4 + 2], w.z, fmaf(hs[d4 * 4 + 3], w.w, acc))));
            }
            red[tid] = acc;   // red holds g
        }
        __syncthreads();
        // ---- LSTM cell (threads 0..127)
        if (tid < HH) {
            float i_ = 1.f / (1.f + expf(-red[tid]));
            float f_ = 1.f / (1.f + expf(-red[HH + tid]));
            float g_ = tanhf(red[2 * HH + tid]);
            float o_ = 1.f / (1.f + expf(-red[3 * HH + tid]));
            float c2 = f_ * cs[tid] + i_ * g_;
            cs[tid] = c2;
            hs[tid] = o_ * tanhf(c2);
        }
        __syncthreads();
        // ---- attention logits, n = tid
        {
            const us4* vh4 = reinterpret_cast<const us4*>(mh + (size_t)tid * HH);
            const us4* vl4 = reinterpret_cast<const us4*>(ml + (size_t)tid * HH);
            float acc = 0.f;
            #pragma unroll 8
            for (int d4 = 0; d4 < HH / 4; ++d4) {
                us4 a = vh4[d4], l = vl4[d4];
                #pragma unroll
                for (int j = 0; j < 4; ++j)
                    acc = fmaf(bf2f(a[j]) + bf2f(l[j]), hs[d4 * 4 + j], acc);
            }
            att[tid] = acc;
            red[tid] = acc;
        }
        __syncthreads();
        // ---- softmax max
        for (int s = 256; s > 0; s >>= 1) {
            if (tid < s) red[tid] = fmaxf(red[tid], red[tid + s]);
            __syncthreads();
        }
        float mx = red[0];
        __syncthreads();
        float ev = expf(att[tid] - mx);
        att[tid] = ev;
        red[tid] = ev;
        __syncthreads();
        for (int s = 256; s > 0; s >>= 1) {
            if (tid < s) red[tid] += red[tid + s];
            __syncthreads();
        }
        float inv = 1.f / red[0];
        __syncthreads();
        // ---- read vector: thread = (h = tid&127, quarter = tid>>7)
        {
            int hidx = tid & 127, nq = tid >> 7;
            float racc = 0.f;
            #pragma unroll 4
            for (int i = 0; i < 128; ++i) {
                int n = nq * 128 + i;
                racc = fmaf(att[n], bf2f(mh[(size_t)n * HH + hidx]) + bf2f(ml[(size_t)n * HH + hidx]), racc);
            }
            red[tid] = racc;
        }
        __syncthreads();
        if (tid < HH) {
            float r = (red[tid] + red[128 + tid] + red[256 + tid] + red[384 + tid]) * inv;
            q[tid] = hs[tid];
            q[HH + tid] = r;
        }
        __syncthreads();
    }
    if (tid < DOUT) {
        float acc = bout[tid];
        const float4* w = reinterpret_cast<const float4*>(Wout + (size_t)tid * 256);
        #pragma unroll 8
        for (int d4 = 0; d4 < 64; ++d4) {
            float4 wv = w[d4];
            acc = fmaf(q[d4 * 4 + 0], wv.x, fmaf(q[d4 * 4 + 1], wv.y,
                  fmaf(q[d4 * 4 + 2], wv.z, fmaf(q[d4 * 4 + 3], wv.w, acc))));
        }
        out[b * DOUT + tid] = acc;
    }
}

extern "C" void kernel_launch(void* const* d_in, const int* in_sizes, int n_in,
                              void* d_out, int out_size, void* d_ws, size_t ws_size,
                              hipStream_t stream) {
    const int*   node_feat = (const int*)d_in[0];
    const float* L         = (const float*)d_in[1];
    const float* node_emb  = (const float*)d_in[2];
    const float* W_in      = (const float*)d_in[3];
    const float* b_in      = (const float*)d_in[4];
    const float* edge_emb  = (const float*)d_in[5];
    const float* gru_wih   = (const float*)d_in[6];
    const float* gru_whh   = (const float*)d_in[7];
    const float* gru_bih   = (const float*)d_in[8];
    const float* gru_bhh   = (const float*)d_in[9];
    const float* lstm_wih  = (const float*)d_in[10];
    const float* lstm_whh  = (const float*)d_in[11];
    const float* lstm_bih  = (const float*)d_in[12];
    const float* lstm_bhh  = (const float*)d_in[13];
    const float* W_out     = (const float*)d_in[14];
    const float* b_out     = (const float*)d_in[15];
    float* out = (float*)d_out;

    char* ws = (char*)d_ws;
    // layout (MiB): 0 state_hi(4) | 4 state_lo(4) | 8 stateT_hi(4) | 12 stateT_lo(4)
    //               16 Abits(4) | 20 S2_hi(8) | 28 S2_lo(8) | 36 gi f32(12) | 48 gh f32(12)
    //               60 weights (~1)
    ushort_t* state_hi  = (ushort_t*)ws;
    ushort_t* stateT_hi = (ushort_t*)(ws + (8u << 20));
    unsigned* Abits     = (unsigned*)(ws + (16u << 20));
    ushort_t* S2        = (ushort_t*)(ws + (20u << 20));
    float*    gi        = (float*)(ws + (36u << 20));
    float*    gh        = (float*)(ws + (48u << 20));
    ushort_t* U_h       = (ushort_t*)(ws + (60u << 20));
    ushort_t* U_l       = U_h + 196608;
    ushort_t* whh_h     = U_l + 196608;
    ushort_t* whh_l     = whh_h + 49152;

    const size_t SPLANE = 2097152;    // state/stateT plane stride (elems)
    const size_t S2PLANE = 4194304;   // S2 plane stride (elems, per half: 8192*512)

    pack_A_kernel<<<(BB * NN * 16) / 256, 256, 0, stream>>>(L, Abits);
    convW_kernel<<<(384 * 512 + 384 * 128) / 256, 256, 0, stream>>>(
        edge_emb, gru_wih, gru_whh, U_h, U_l, whh_h, whh_l);
    embed_kernel<<<BB * NN, 128, 0, stream>>>(node_feat, node_emb, W_in, b_in,
                                              state_hi, state_hi + SPLANE);

    for (int p = 0; p < NPROP; ++p) {
        // stateT[h][row] (full batch, both planes)
        transpose_kernel<<<256, 256, 0, stream>>>(state_hi, stateT_hi, SPLANE);
        for (int half = 0; half < 2; ++half) {
            const unsigned* Ab = Abits + (size_t)half * 16 * E1 * NN * 16;
            const ushort_t* Xst = state_hi + (size_t)half * MHALF * HH;
            size_t half_off = (size_t)half * MHALF * HH;
            // S2[(bl*512+m)][e*128+h] = A_be @ state_b : per z M=512, N=128, K=512
            mm_kernel<4, true, true, 512, false, true><<<dim3(2, 4, 64), 256, 0, stream>>>(
                Ab, 0, stateT_hi + (size_t)half * MHALF, SPLANE, nullptr,
                S2, S2PLANE, 0, 16384, 512);
            // gi = S2 @ U^T + bih : M=8192, N=384, K=512 -> fp32
            mm_kernel<3, false, false, 512, true, true><<<dim3(6, 64), 256, 0, stream>>>(
                S2, S2PLANE, U_h, 196608, gru_bih, gi, 0, 512, 512, 384);
            // gh = state @ whh^T + bhh : M=8192, N=384, K=128 -> fp32
            mm_kernel<3, false, false, 128, true, true><<<dim3(6, 64), 256, 0, stream>>>(
                Xst, SPLANE, whh_h, 49152, gru_bhh, gh, 0, 128, 128, 384);
            // gates -> state planes
            gru_gate_kernel<<<(MHALF * HH) / 256, 256, 0, stream>>>(gi, gh, state_hi,
                                                                    state_hi + SPLANE, half_off);
        }
    }

    s2v_kernel<<<BB, 512, 0, stream>>>(state_hi, state_hi + SPLANE, lstm_wih, lstm_whh,
                                       lstm_bih, lstm_bhh, W_out, b_out, out);
}